// Round 3
// baseline (901.221 us; speedup 1.0000x reference)
//
#include <hip/hip_runtime.h>
#include <cstdint>

typedef unsigned short u16;
typedef unsigned int   u32;
typedef __bf16 bf16x8 __attribute__((ext_vector_type(8)));
typedef float  f32x4  __attribute__((ext_vector_type(4)));

#define NCTX 10
#define BSZ  32
#define IDF  256
#define QSZ  1024
#define CDF  512
#define LSZ  128

__device__ __forceinline__ u16 f2bf(float f) {
    u32 u = __float_as_uint(f);
    u += 0x7FFFu + ((u >> 16) & 1u);          // RNE to bf16
    return (u16)(u >> 16);
}
__device__ __forceinline__ float bf2f(u16 h) {
    return __uint_as_float(((u32)h) << 16);
}

union U4V { uint4 u; bf16x8 v; };

__device__ __forceinline__ bf16x8 ldg16(const u16* p) {   // 8 contiguous bf16 (16B)
    U4V t; t.u = *(const uint4*)p; return t.v;
}
__device__ __forceinline__ bf16x8 lds16(const u16* p) {   // 8 contiguous bf16 from LDS
    U4V t; t.u = *(const uint4*)p; return t.v;
}
__device__ __forceinline__ f32x4 mfma16(bf16x8 a, bf16x8 b, f32x4 c) {
    return __builtin_amdgcn_mfma_f32_16x16x32_bf16(a, b, c, 0, 0, 0);
}

// ---------------- K1a: weights -> bf16 (Wc hi/lo, Wcat plain) ----------------
__global__ __launch_bounds__(256) void k1a_conv(const float* __restrict__ Wc,
                                                const float* __restrict__ Wcat,
                                                u16* __restrict__ Wc_hi,
                                                u16* __restrict__ Wc_lo,
                                                u16* __restrict__ Wcat_bf) {
    int i = blockIdx.x * 256 + threadIdx.x;
    if (i < IDF * CDF) {
        float f = Wc[i];
        u16 h = f2bf(f);
        Wc_hi[i] = h;
        Wc_lo[i] = f2bf(f - bf2f(h));
    } else {
        int j = i - IDF * CDF;
        Wcat_bf[j] = f2bf(Wcat[j]);
    }
}

// ---------------- K1b: input [B,idf,Q] -> T_hi/T_lo [B,Q,idf] ----------------
// Tile 32 d x 128 q; float4 loads, uint4 stores.
__global__ __launch_bounds__(256) void k1b_tgt(const float* __restrict__ input,
                                               u16* __restrict__ T_hi,
                                               u16* __restrict__ T_lo) {
    __shared__ float t[32 * 132];
    const int tid = threadIdx.x;
    const int qt = blockIdx.x, dt = blockIdx.y, b = blockIdx.z;
#pragma unroll
    for (int k = 0; k < 4; ++k) {
        const int idx = tid + k * 256;
        const int d = idx >> 5, c4 = idx & 31;
        const float4 v = *(const float4*)(input +
            ((long)(b * IDF + dt * 32 + d)) * QSZ + qt * 128 + c4 * 4);
        *(float4*)(t + d * 132 + c4 * 4) = v;
    }
    __syncthreads();
#pragma unroll
    for (int k = 0; k < 2; ++k) {
        const int idx = tid + k * 256;            // 512 tasks
        const int q = idx >> 2, dg = idx & 3;
        u16 hi[8], lo[8];
#pragma unroll
        for (int jj = 0; jj < 8; ++jj) {
            float f = t[(dg * 8 + jj) * 132 + q];
            u16 h = f2bf(f);
            hi[jj] = h;
            lo[jj] = f2bf(f - bf2f(h));
        }
        const long o = ((long)(b * QSZ + qt * 128 + q)) * IDF + dt * 32 + dg * 8;
        *(uint4*)(T_hi + o) = *(const uint4*)hi;
        *(uint4*)(T_lo + o) = *(const uint4*)lo;
    }
}

// ---------------- K1c: contexts [n,b,c,l] -> ctxT bf16 [n,b,l,c] -------------
// Tile 32 c x 128 l (full l); float4 loads, uint4 stores.
__global__ __launch_bounds__(256) void k1c_ctx(const float* __restrict__ ctx,
                                               u16* __restrict__ ctxT) {
    __shared__ float t[32 * 132];
    const int tid = threadIdx.x;
    const int ct = blockIdx.x, nb = blockIdx.y;
#pragma unroll
    for (int k = 0; k < 4; ++k) {
        const int idx = tid + k * 256;
        const int c = idx >> 5, l4 = idx & 31;
        const float4 v = *(const float4*)(ctx +
            ((long)(nb * CDF + ct * 32 + c)) * LSZ + l4 * 4);
        *(float4*)(t + c * 132 + l4 * 4) = v;
    }
    __syncthreads();
#pragma unroll
    for (int k = 0; k < 2; ++k) {
        const int idx = tid + k * 256;            // 512 tasks
        const int l = idx >> 2, dg = idx & 3;
        u16 bv[8];
#pragma unroll
        for (int jj = 0; jj < 8; ++jj)
            bv[jj] = f2bf(t[(dg * 8 + jj) * 132 + l]);
        *(uint4*)(ctxT + ((long)(nb * LSZ + l)) * CDF + ct * 32 + dg * 8) =
            *(const uint4*)bv;
    }
}

// ---------------- K2: sourceT = Wc @ ctx  (per (n,b), hi/lo x hi) ------------
__global__ __launch_bounds__(256, 2) void k2_src(const u16* __restrict__ Wc_hi,
                                                 const u16* __restrict__ Wc_lo,
                                                 const u16* __restrict__ ctxT,
                                                 u16* __restrict__ sTT_hi,
                                                 u16* __restrict__ sTT_lo,
                                                 u16* __restrict__ s_dl) {
    __shared__ u16 bounce[128 * 136];
    const int tid = threadIdx.x;
    const int L = tid & 63, w = tid >> 6;
    const int wd = w >> 1, wl = w & 1, lr = L & 15, quad = L >> 4;
    const int dbase = blockIdx.x * 128;
    const int nb = blockIdx.y;
    const u16* ctxb = ctxT + (long)nb * LSZ * CDF;

    const f32x4 vz = {0.f, 0.f, 0.f, 0.f};
    f32x4 acc[4][4];
#pragma unroll
    for (int m = 0; m < 4; ++m)
#pragma unroll
        for (int nn = 0; nn < 4; ++nn) acc[m][nn] = vz;

    for (int kc = 0; kc < 16; ++kc) {
        const int c0 = kc * 32 + quad * 8;
        bf16x8 aH[4], aL[4], bb[4];
#pragma unroll
        for (int m = 0; m < 4; ++m) {
            const int d = dbase + 64 * wd + 16 * m + lr;
            aH[m] = ldg16(Wc_hi + d * CDF + c0);
            aL[m] = ldg16(Wc_lo + d * CDF + c0);
        }
#pragma unroll
        for (int nn = 0; nn < 4; ++nn) {
            const int l = 64 * wl + 16 * nn + lr;
            bb[nn] = ldg16(ctxb + l * CDF + c0);
        }
#pragma unroll
        for (int m = 0; m < 4; ++m)
#pragma unroll
            for (int nn = 0; nn < 4; ++nn) {
                acc[m][nn] = mfma16(aH[m], bb[nn], acc[m][nn]);
                acc[m][nn] = mfma16(aL[m], bb[nn], acc[m][nn]);
            }
    }

    // pass 1: hi, transposed [l][d]
#pragma unroll
    for (int m = 0; m < 4; ++m)
#pragma unroll
        for (int nn = 0; nn < 4; ++nn)
#pragma unroll
            for (int r = 0; r < 4; ++r) {
                const int d = 64 * wd + 16 * m + 4 * quad + r;
                const int l = 64 * wl + 16 * nn + lr;
                bounce[l * 136 + d] = f2bf(acc[m][nn][r]);
            }
    __syncthreads();
    for (int i = tid; i < 2048; i += 256) {
        const int l = i >> 4, g = (i & 15) * 8;
        *(uint4*)(sTT_hi + ((long)nb * LSZ + l) * IDF + dbase + g) =
            *(const uint4*)(bounce + l * 136 + g);
    }
    __syncthreads();
    // pass 2: lo, transposed [l][d]
#pragma unroll
    for (int m = 0; m < 4; ++m)
#pragma unroll
        for (int nn = 0; nn < 4; ++nn)
#pragma unroll
            for (int r = 0; r < 4; ++r) {
                const int d = 64 * wd + 16 * m + 4 * quad + r;
                const int l = 64 * wl + 16 * nn + lr;
                float c = acc[m][nn][r];
                u16 h = f2bf(c);
                bounce[l * 136 + d] = f2bf(c - bf2f(h));
            }
    __syncthreads();
    for (int i = tid; i < 2048; i += 256) {
        const int l = i >> 4, g = (i & 15) * 8;
        *(uint4*)(sTT_lo + ((long)nb * LSZ + l) * IDF + dbase + g) =
            *(const uint4*)(bounce + l * 136 + g);
    }
    __syncthreads();
    // pass 3: hi, natural [d][l]
#pragma unroll
    for (int m = 0; m < 4; ++m)
#pragma unroll
        for (int nn = 0; nn < 4; ++nn)
#pragma unroll
            for (int r = 0; r < 4; ++r) {
                const int d = 64 * wd + 16 * m + 4 * quad + r;
                const int l = 64 * wl + 16 * nn + lr;
                bounce[d * 136 + l] = f2bf(acc[m][nn][r]);
            }
    __syncthreads();
    for (int i = tid; i < 2048; i += 256) {
        const int d = i >> 4, g = (i & 15) * 8;
        *(uint4*)(s_dl + ((long)nb * IDF + dbase + d) * LSZ + g) =
            *(const uint4*)(bounce + d * 136 + g);
    }
}

// ---------------- K3: fused scores->softmax->PV->concat-proj->LN -------------
// 32-row q tiles, 1024 blocks (4/CU). Register softmax (no max-sub), 2 barriers/n.
// XCD swizzle: blocks sharing b land on one XCD.
__global__ __launch_bounds__(256, 4) void k3_attn(
    const u16* __restrict__ T_hi, const u16* __restrict__ T_lo,
    const u16* __restrict__ sTT_hi, const u16* __restrict__ sTT_lo,
    const u16* __restrict__ s_dl, const u16* __restrict__ Wcat_bf,
    const float* __restrict__ Wb, const float* __restrict__ gam_p,
    const float* __restrict__ bet_p, float* __restrict__ out)
{
    __shared__ __align__(16) u16 E[32 * 136];      // exp(S), unnormalized, A-layout
    __shared__ __align__(16) u16 attnL[32 * 264];  // normalized attn bf16
    __shared__ __align__(16) float red[32 * 8];

    const int tid = threadIdx.x;
    const int L = tid & 63, w = tid >> 6;
    const int lr = L & 15, quad = L >> 4;
    // XCD-aware mapping: block i -> xcd i&7; each XCD owns 4 consecutive b.
    const int i = blockIdx.x;
    const int xcd = i & 7, j = i >> 3;
    const int b = xcd * 4 + (j >> 5);
    const int qt = j & 31;
    const int bq = b * QSZ + qt * 32;

    const f32x4 vz = {0.f, 0.f, 0.f, 0.f};
    f32x4 x_acc[2][4];
#pragma unroll
    for (int m = 0; m < 2; ++m)
#pragma unroll
        for (int nn = 0; nn < 4; ++nn) x_acc[m][nn] = vz;

    for (int n = 0; n < NCTX; ++n) {
        const int nb = n * BSZ + b;
        const u16* sttH = sTT_hi + (long)nb * (LSZ * IDF);
        const u16* sttL = sTT_lo + (long)nb * (LSZ * IDF);
        const u16* sdl  = s_dl  + (long)nb * (IDF * LSZ);
        const u16* wcat = Wcat_bf + n * IDF;

        // ---- phase 1: S[32q x 128l]; wave w owns l-strip [32w, 32w+32)
        f32x4 s_acc[2][2];
#pragma unroll
        for (int m = 0; m < 2; ++m)
#pragma unroll
            for (int nn = 0; nn < 2; ++nn) s_acc[m][nn] = vz;

        for (int kc = 0; kc < 8; ++kc) {
            const int c0 = kc * 32 + quad * 8;
            bf16x8 aH[2], aL[2], bH[2], bL[2];
#pragma unroll
            for (int m = 0; m < 2; ++m) {
                const long ro = (long)(bq + 16 * m + lr) * IDF + c0;
                aH[m] = ldg16(T_hi + ro);
                aL[m] = ldg16(T_lo + ro);
            }
#pragma unroll
            for (int nn = 0; nn < 2; ++nn) {
                const long ro = (long)(32 * w + 16 * nn + lr) * IDF + c0;
                bH[nn] = ldg16(sttH + ro);
                bL[nn] = ldg16(sttL + ro);
            }
#pragma unroll
            for (int m = 0; m < 2; ++m)
#pragma unroll
                for (int nn = 0; nn < 2; ++nn) {
                    s_acc[m][nn] = mfma16(aH[m], bH[nn], s_acc[m][nn]);
                    s_acc[m][nn] = mfma16(aH[m], bL[nn], s_acc[m][nn]);
                    s_acc[m][nn] = mfma16(aL[m], bH[nn], s_acc[m][nn]);
                }
        }

        // ---- softmax in registers (no max-sub; |S| << 88 so exp is safe)
        float rs_[2][4];
#pragma unroll
        for (int m = 0; m < 2; ++m)
#pragma unroll
            for (int r = 0; r < 4; ++r) rs_[m][r] = 0.f;
#pragma unroll
        for (int m = 0; m < 2; ++m)
#pragma unroll
            for (int nn = 0; nn < 2; ++nn)
#pragma unroll
                for (int r = 0; r < 4; ++r) {
                    const float e = __expf(s_acc[m][nn][r]);
                    rs_[m][r] += e;
                    E[(16 * m + 4 * quad + r) * 136 + 32 * w + 16 * nn + lr] = f2bf(e);
                }
#pragma unroll
        for (int off = 1; off <= 8; off <<= 1)
#pragma unroll
            for (int m = 0; m < 2; ++m)
#pragma unroll
                for (int r = 0; r < 4; ++r)
                    rs_[m][r] += __shfl_xor(rs_[m][r], off);
        if (lr == 0) {
#pragma unroll
            for (int m = 0; m < 2; ++m)
#pragma unroll
                for (int r = 0; r < 4; ++r)
                    red[(16 * m + 4 * quad + r) * 4 + w] = rs_[m][r];
        }
        __syncthreads();                          // B1: E + partial sums ready

        float invr[2][4];
#pragma unroll
        for (int m = 0; m < 2; ++m)
#pragma unroll
            for (int r = 0; r < 4; ++r) {
                const float4 rv = *(const float4*)(red + (16 * m + 4 * quad + r) * 4);
                invr[m][r] = 1.0f / (rv.x + rv.y + rv.z + rv.w);
            }

        // ---- phase 2: attn[32q x 256d]; wave w owns d-strip [64w, 64w+64)
        f32x4 a_acc[2][4];
#pragma unroll
        for (int m = 0; m < 2; ++m)
#pragma unroll
            for (int nn = 0; nn < 4; ++nn) a_acc[m][nn] = vz;

        for (int kc = 0; kc < 4; ++kc) {
            const int l0 = kc * 32 + quad * 8;
            bf16x8 af[2], bf[4];
#pragma unroll
            for (int m = 0; m < 2; ++m)
                af[m] = lds16(E + (16 * m + lr) * 136 + l0);
#pragma unroll
            for (int nn = 0; nn < 4; ++nn) {
                const int d = 64 * w + 16 * nn + lr;
                bf[nn] = ldg16(sdl + d * LSZ + l0);
            }
#pragma unroll
            for (int m = 0; m < 2; ++m)
#pragma unroll
                for (int nn = 0; nn < 4; ++nn)
                    a_acc[m][nn] = mfma16(af[m], bf[nn], a_acc[m][nn]);
        }
#pragma unroll
        for (int m = 0; m < 2; ++m)
#pragma unroll
            for (int nn = 0; nn < 4; ++nn)
#pragma unroll
                for (int r = 0; r < 4; ++r)
                    attnL[(16 * m + 4 * quad + r) * 264 + 64 * w + 16 * nn + lr] =
                        f2bf(a_acc[m][nn][r] * invr[m][r]);
        __syncthreads();                          // B2: attn ready

        // ---- phase 3: X[32q x 256e] += attn . Wcat_n^T; wave w owns e-strip
        for (int kc = 0; kc < 8; ++kc) {
            const int d0 = kc * 32 + quad * 8;
            bf16x8 af[2], bf[4];
#pragma unroll
            for (int m = 0; m < 2; ++m)
                af[m] = lds16(attnL + (16 * m + lr) * 264 + d0);
#pragma unroll
            for (int nn = 0; nn < 4; ++nn) {
                const int e = 64 * w + 16 * nn + lr;
                bf[nn] = ldg16(wcat + e * (NCTX * IDF) + d0);
            }
#pragma unroll
            for (int m = 0; m < 2; ++m)
#pragma unroll
                for (int nn = 0; nn < 4; ++nn)
                    x_acc[m][nn] = mfma16(af[m], bf[nn], x_acc[m][nn]);
        }
        // next n's E/red writes are fenced by B2 (phase-2 E reads + red reads done),
        // and next n's attnL writes are fenced by its own B1.
    }

    // ---- epilogue: bias + relu + residual + LayerNorm(eps=0) ----
    float gv[4], bv[4], wv[4];
    int ec[4];
#pragma unroll
    for (int nn = 0; nn < 4; ++nn) {
        ec[nn] = 64 * w + 16 * nn + lr;
        wv[nn] = Wb[ec[nn]];
        gv[nn] = gam_p[ec[nn]];
        bv[nn] = bet_p[ec[nn]];
    }
    float s1[2][4], s2[2][4];
#pragma unroll
    for (int m = 0; m < 2; ++m)
#pragma unroll
        for (int r = 0; r < 4; ++r) {
            const int row = 16 * m + 4 * quad + r;
            const u16* th = T_hi + (long)(bq + row) * IDF;
            const u16* tl = T_lo + (long)(bq + row) * IDF;
            float a = 0.f, q2 = 0.f;
#pragma unroll
            for (int nn = 0; nn < 4; ++nn) {
                const float resid = bf2f(th[ec[nn]]) + bf2f(tl[ec[nn]]);
                const float v = fmaxf(x_acc[m][nn][r] + wv[nn], 0.f) + resid;
                x_acc[m][nn][r] = v;
                a += v;
                q2 += v * v;
            }
            s1[m][r] = a;
            s2[m][r] = q2;
        }
#pragma unroll
    for (int off = 1; off <= 8; off <<= 1)
#pragma unroll
        for (int m = 0; m < 2; ++m)
#pragma unroll
            for (int r = 0; r < 4; ++r) {
                s1[m][r] += __shfl_xor(s1[m][r], off);
                s2[m][r] += __shfl_xor(s2[m][r], off);
            }
    if (lr == 0) {
#pragma unroll
        for (int m = 0; m < 2; ++m)
#pragma unroll
            for (int r = 0; r < 4; ++r) {
                const int row = 16 * m + 4 * quad + r;
                red[row * 8 + w * 2]     = s1[m][r];
                red[row * 8 + w * 2 + 1] = s2[m][r];
            }
    }
    __syncthreads();
#pragma unroll
    for (int m = 0; m < 2; ++m)
#pragma unroll
        for (int r = 0; r < 4; ++r) {
            const int row = 16 * m + 4 * quad + r;
            const float4 pa = *(const float4*)(red + row * 8);
            const float4 pb = *(const float4*)(red + row * 8 + 4);
            const float S1 = pa.x + pa.z + pb.x + pb.z;
            const float S2 = pa.y + pa.w + pb.y + pb.w;
            const float mu = S1 * (1.f / 256.f);
            const float rs = rsqrtf(S2 * (1.f / 256.f) - mu * mu);
            float* op = out + (long)(bq + row) * IDF;
#pragma unroll
            for (int nn = 0; nn < 4; ++nn)
                op[ec[nn]] = (x_acc[m][nn][r] - mu) * rs * gv[nn] + bv[nn];
        }
}

// ---------------- launch ----------------
extern "C" void kernel_launch(void* const* d_in, const int* in_sizes, int n_in,
                              void* d_out, int out_size, void* d_ws, size_t ws_size,
                              hipStream_t stream) {
    const float* input    = (const float*)d_in[0];
    const float* contexts = (const float*)d_in[1];
    const float* Wc       = (const float*)d_in[2];
    const float* Wcat     = (const float*)d_in[3];
    const float* Wb       = (const float*)d_in[4];
    const float* gamma    = (const float*)d_in[5];
    const float* beta     = (const float*)d_in[6];
    float* out = (float*)d_out;

    char* ws = (char*)d_ws;
    size_t off = 0;
    u16* Wc_hi   = (u16*)(ws + off); off += (size_t)IDF * CDF * 2;
    u16* Wc_lo   = (u16*)(ws + off); off += (size_t)IDF * CDF * 2;
    u16* Wcat_bf = (u16*)(ws + off); off += (size_t)IDF * NCTX * IDF * 2;
    u16* T_hi    = (u16*)(ws + off); off += (size_t)BSZ * QSZ * IDF * 2;
    u16* T_lo    = (u16*)(ws + off); off += (size_t)BSZ * QSZ * IDF * 2;
    u16* ctxT    = (u16*)(ws + off); off += (size_t)NCTX * BSZ * LSZ * CDF * 2;
    u16* sTT_hi  = (u16*)(ws + off); off += (size_t)NCTX * BSZ * LSZ * IDF * 2;
    u16* sTT_lo  = (u16*)(ws + off); off += (size_t)NCTX * BSZ * LSZ * IDF * 2;
    u16* s_dl    = (u16*)(ws + off); off += (size_t)NCTX * BSZ * IDF * LSZ * 2;
    (void)in_sizes; (void)n_in; (void)out_size; (void)ws_size;

    k1a_conv<<<3072, 256, 0, stream>>>(Wc, Wcat, Wc_hi, Wc_lo, Wcat_bf);
    k1b_tgt<<<dim3(QSZ / 128, IDF / 32, BSZ), 256, 0, stream>>>(input, T_hi, T_lo);
    k1c_ctx<<<dim3(CDF / 32, NCTX * BSZ), 256, 0, stream>>>(contexts, ctxT);
    k2_src<<<dim3(2, NCTX * BSZ), 256, 0, stream>>>(Wc_hi, Wc_lo, ctxT, sTT_hi, sTT_lo, s_dl);
    k3_attn<<<dim3(1024), 256, 0, stream>>>(T_hi, T_lo, sTT_hi, sTT_lo, s_dl,
                                            Wcat_bf, Wb, gamma, beta, out);
}

// Round 4
// 772.307 us; speedup vs baseline: 1.1669x; 1.1669x over previous
//
#include <hip/hip_runtime.h>
#include <cstdint>

typedef unsigned short u16;
typedef unsigned int   u32;
typedef __bf16 bf16x8 __attribute__((ext_vector_type(8)));
typedef float  f32x4  __attribute__((ext_vector_type(4)));

#define NCTX 10
#define BSZ  32
#define IDF  256
#define QSZ  1024
#define CDF  512
#define LSZ  128

__device__ __forceinline__ u16 f2bf(float f) {
    u32 u = __float_as_uint(f);
    u += 0x7FFFu + ((u >> 16) & 1u);          // RNE to bf16
    return (u16)(u >> 16);
}
__device__ __forceinline__ float bf2f(u16 h) {
    return __uint_as_float(((u32)h) << 16);
}

union U4V { uint4 u; bf16x8 v; };

__device__ __forceinline__ bf16x8 ldg16(const u16* p) {   // 8 contiguous bf16 (16B)
    U4V t; t.u = *(const uint4*)p; return t.v;
}
__device__ __forceinline__ bf16x8 lds16(const u16* p) {
    U4V t; t.u = *(const uint4*)p; return t.v;
}
__device__ __forceinline__ f32x4 mfma16(bf16x8 a, bf16x8 b, f32x4 c) {
    return __builtin_amdgcn_mfma_f32_16x16x32_bf16(a, b, c, 0, 0, 0);
}

// ---------------- K1a: weights -> bf16 (Wc hi/lo, Wcat plain) ----------------
__global__ __launch_bounds__(256) void k1a_conv(const float* __restrict__ Wc,
                                                const float* __restrict__ Wcat,
                                                u16* __restrict__ Wc_hi,
                                                u16* __restrict__ Wc_lo,
                                                u16* __restrict__ Wcat_bf) {
    int i = blockIdx.x * 256 + threadIdx.x;
    if (i < IDF * CDF) {
        float f = Wc[i];
        u16 h = f2bf(f);
        Wc_hi[i] = h;
        Wc_lo[i] = f2bf(f - bf2f(h));
    } else {
        int j = i - IDF * CDF;
        Wcat_bf[j] = f2bf(Wcat[j]);
    }
}

// ---------------- K1b: input [B,idf,Q] -> T_hi/T_lo [B,Q,idf] ----------------
__global__ __launch_bounds__(256) void k1b_tgt(const float* __restrict__ input,
                                               u16* __restrict__ T_hi,
                                               u16* __restrict__ T_lo) {
    __shared__ float t[32 * 132];
    const int tid = threadIdx.x;
    const int qt = blockIdx.x, dt = blockIdx.y, b = blockIdx.z;
#pragma unroll
    for (int k = 0; k < 4; ++k) {
        const int idx = tid + k * 256;
        const int d = idx >> 5, c4 = idx & 31;
        const float4 v = *(const float4*)(input +
            ((long)(b * IDF + dt * 32 + d)) * QSZ + qt * 128 + c4 * 4);
        *(float4*)(t + d * 132 + c4 * 4) = v;
    }
    __syncthreads();
#pragma unroll
    for (int k = 0; k < 2; ++k) {
        const int idx = tid + k * 256;
        const int q = idx >> 2, dg = idx & 3;
        u16 hi[8], lo[8];
#pragma unroll
        for (int jj = 0; jj < 8; ++jj) {
            float f = t[(dg * 8 + jj) * 132 + q];
            u16 h = f2bf(f);
            hi[jj] = h;
            lo[jj] = f2bf(f - bf2f(h));
        }
        const long o = ((long)(b * QSZ + qt * 128 + q)) * IDF + dt * 32 + dg * 8;
        *(uint4*)(T_hi + o) = *(const uint4*)hi;
        *(uint4*)(T_lo + o) = *(const uint4*)lo;
    }
}

// ---------------- K1c: contexts [n,b,c,l] -> ctxT bf16 [n,b,l,c] -------------
__global__ __launch_bounds__(256) void k1c_ctx(const float* __restrict__ ctx,
                                               u16* __restrict__ ctxT) {
    __shared__ float t[32 * 132];
    const int tid = threadIdx.x;
    const int ct = blockIdx.x, nb = blockIdx.y;
#pragma unroll
    for (int k = 0; k < 4; ++k) {
        const int idx = tid + k * 256;
        const int c = idx >> 5, l4 = idx & 31;
        const float4 v = *(const float4*)(ctx +
            ((long)(nb * CDF + ct * 32 + c)) * LSZ + l4 * 4);
        *(float4*)(t + c * 132 + l4 * 4) = v;
    }
    __syncthreads();
#pragma unroll
    for (int k = 0; k < 2; ++k) {
        const int idx = tid + k * 256;
        const int l = idx >> 2, dg = idx & 3;
        u16 bv[8];
#pragma unroll
        for (int jj = 0; jj < 8; ++jj)
            bv[jj] = f2bf(t[(dg * 8 + jj) * 132 + l]);
        *(uint4*)(ctxT + ((long)(nb * LSZ + l)) * CDF + ct * 32 + dg * 8) =
            *(const uint4*)bv;
    }
}

// ---------------- K2: sourceT = Wc @ ctx  (per (n,b), hi/lo x hi) ------------
__global__ __launch_bounds__(256, 2) void k2_src(const u16* __restrict__ Wc_hi,
                                                 const u16* __restrict__ Wc_lo,
                                                 const u16* __restrict__ ctxT,
                                                 u16* __restrict__ sTT_hi,
                                                 u16* __restrict__ sTT_lo,
                                                 u16* __restrict__ s_dl) {
    __shared__ u16 bounce[128 * 136];
    const int tid = threadIdx.x;
    const int L = tid & 63, w = tid >> 6;
    const int wd = w >> 1, wl = w & 1, lr = L & 15, quad = L >> 4;
    const int dbase = blockIdx.x * 128;
    const int nb = blockIdx.y;
    const u16* ctxb = ctxT + (long)nb * LSZ * CDF;

    const f32x4 vz = {0.f, 0.f, 0.f, 0.f};
    f32x4 acc[4][4];
#pragma unroll
    for (int m = 0; m < 4; ++m)
#pragma unroll
        for (int nn = 0; nn < 4; ++nn) acc[m][nn] = vz;

    for (int kc = 0; kc < 16; ++kc) {
        const int c0 = kc * 32 + quad * 8;
        bf16x8 aH[4], aL[4], bb[4];
#pragma unroll
        for (int m = 0; m < 4; ++m) {
            const int d = dbase + 64 * wd + 16 * m + lr;
            aH[m] = ldg16(Wc_hi + d * CDF + c0);
            aL[m] = ldg16(Wc_lo + d * CDF + c0);
        }
#pragma unroll
        for (int nn = 0; nn < 4; ++nn) {
            const int l = 64 * wl + 16 * nn + lr;
            bb[nn] = ldg16(ctxb + l * CDF + c0);
        }
#pragma unroll
        for (int m = 0; m < 4; ++m)
#pragma unroll
            for (int nn = 0; nn < 4; ++nn) {
                acc[m][nn] = mfma16(aH[m], bb[nn], acc[m][nn]);
                acc[m][nn] = mfma16(aL[m], bb[nn], acc[m][nn]);
            }
    }

    // pass 1: hi, transposed [l][d]
#pragma unroll
    for (int m = 0; m < 4; ++m)
#pragma unroll
        for (int nn = 0; nn < 4; ++nn)
#pragma unroll
            for (int r = 0; r < 4; ++r) {
                const int d = 64 * wd + 16 * m + 4 * quad + r;
                const int l = 64 * wl + 16 * nn + lr;
                bounce[l * 136 + d] = f2bf(acc[m][nn][r]);
            }
    __syncthreads();
    for (int i = tid; i < 2048; i += 256) {
        const int l = i >> 4, g = (i & 15) * 8;
        *(uint4*)(sTT_hi + ((long)nb * LSZ + l) * IDF + dbase + g) =
            *(const uint4*)(bounce + l * 136 + g);
    }
    __syncthreads();
    // pass 2: lo, transposed [l][d]
#pragma unroll
    for (int m = 0; m < 4; ++m)
#pragma unroll
        for (int nn = 0; nn < 4; ++nn)
#pragma unroll
            for (int r = 0; r < 4; ++r) {
                const int d = 64 * wd + 16 * m + 4 * quad + r;
                const int l = 64 * wl + 16 * nn + lr;
                float c = acc[m][nn][r];
                u16 h = f2bf(c);
                bounce[l * 136 + d] = f2bf(c - bf2f(h));
            }
    __syncthreads();
    for (int i = tid; i < 2048; i += 256) {
        const int l = i >> 4, g = (i & 15) * 8;
        *(uint4*)(sTT_lo + ((long)nb * LSZ + l) * IDF + dbase + g) =
            *(const uint4*)(bounce + l * 136 + g);
    }
    __syncthreads();
    // pass 3: hi, natural [d][l]
#pragma unroll
    for (int m = 0; m < 4; ++m)
#pragma unroll
        for (int nn = 0; nn < 4; ++nn)
#pragma unroll
            for (int r = 0; r < 4; ++r) {
                const int d = 64 * wd + 16 * m + 4 * quad + r;
                const int l = 64 * wl + 16 * nn + lr;
                bounce[d * 136 + l] = f2bf(acc[m][nn][r]);
            }
    __syncthreads();
    for (int i = tid; i < 2048; i += 256) {
        const int d = i >> 4, g = (i & 15) * 8;
        *(uint4*)(s_dl + ((long)nb * IDF + dbase + d) * LSZ + g) =
            *(const uint4*)(bounce + d * 136 + g);
    }
}

// ---------------- K3: fused scores->softmax->PV->concat-proj->LN -------------
// 128-row q tiles, 512 threads (8 waves), grid 256 = 1 block/CU.
// Waves: wq = w&3 (q-strip of 32), wl = w>>2 (l/d/e strip of 64/128/128).
// 2 barriers per n. XCD grouping: blocks i with i&7==x share XCD x, 4 b's each.
__global__ __launch_bounds__(512, 2) void k3_attn(
    const u16* __restrict__ T_hi, const u16* __restrict__ T_lo,
    const u16* __restrict__ sTT_hi, const u16* __restrict__ sTT_lo,
    const u16* __restrict__ s_dl, const u16* __restrict__ Wcat_bf,
    const float* __restrict__ Wb, const float* __restrict__ gam_p,
    const float* __restrict__ bet_p, float* __restrict__ out)
{
    __shared__ __align__(16) u16 E[128 * 136];      // exp(S), unnormalized (34.8 KB)
    __shared__ __align__(16) u16 attnL[128 * 264];  // normalized attn (67.6 KB)
    __shared__ float red[128 * 2];
    __shared__ float red2[128 * 4];

    const int tid = threadIdx.x;
    const int L = tid & 63, w = tid >> 6;
    const int lr = L & 15, quad = L >> 4;
    const int wq = w & 3, wl = w >> 2;
    const int i = blockIdx.x;
    const int b = (i & 7) * 4 + ((i >> 3) & 3);
    const int qt = i >> 5;                          // 0..7
    const int bq = b * QSZ + qt * 128;

    const f32x4 vz = {0.f, 0.f, 0.f, 0.f};
    f32x4 x_acc[2][8];
#pragma unroll
    for (int m = 0; m < 2; ++m)
#pragma unroll
        for (int nn = 0; nn < 8; ++nn) x_acc[m][nn] = vz;

    for (int n = 0; n < NCTX; ++n) {
        const int nb = n * BSZ + b;
        const u16* sttH = sTT_hi + (long)nb * (LSZ * IDF);
        const u16* sttL = sTT_lo + (long)nb * (LSZ * IDF);
        const u16* sdl  = s_dl  + (long)nb * (IDF * LSZ);
        const u16* wcat = Wcat_bf + n * IDF;

        // ---- phase 1: S[128q x 128l]; wave (wq,wl): q-strip 32, l-strip 64
        f32x4 s_acc[2][4];
#pragma unroll
        for (int m = 0; m < 2; ++m)
#pragma unroll
            for (int nn = 0; nn < 4; ++nn) s_acc[m][nn] = vz;

        for (int kc = 0; kc < 8; ++kc) {
            const int c0 = kc * 32 + quad * 8;
            bf16x8 aH[2], aL[2], bH[4], bL[4];
#pragma unroll
            for (int m = 0; m < 2; ++m) {
                const long ro = (long)(bq + 32 * wq + 16 * m + lr) * IDF + c0;
                aH[m] = ldg16(T_hi + ro);
                aL[m] = ldg16(T_lo + ro);
            }
#pragma unroll
            for (int nn = 0; nn < 4; ++nn) {
                const long ro = (long)(64 * wl + 16 * nn + lr) * IDF + c0;
                bH[nn] = ldg16(sttH + ro);
                bL[nn] = ldg16(sttL + ro);
            }
#pragma unroll
            for (int m = 0; m < 2; ++m)
#pragma unroll
                for (int nn = 0; nn < 4; ++nn) {
                    s_acc[m][nn] = mfma16(aH[m], bH[nn], s_acc[m][nn]);
                    s_acc[m][nn] = mfma16(aH[m], bL[nn], s_acc[m][nn]);
                    s_acc[m][nn] = mfma16(aL[m], bH[nn], s_acc[m][nn]);
                }
        }

        // ---- softmax in registers (no max-sub; |S| <~ 45 << 88 overflow)
        float rs_[2][4];
#pragma unroll
        for (int m = 0; m < 2; ++m)
#pragma unroll
            for (int r = 0; r < 4; ++r) rs_[m][r] = 0.f;
#pragma unroll
        for (int m = 0; m < 2; ++m)
#pragma unroll
            for (int nn = 0; nn < 4; ++nn)
#pragma unroll
                for (int r = 0; r < 4; ++r) {
                    const float e = __expf(s_acc[m][nn][r]);
                    rs_[m][r] += e;
                    E[(32 * wq + 16 * m + 4 * quad + r) * 136 + 64 * wl + 16 * nn + lr]
                        = f2bf(e);
                }
#pragma unroll
        for (int off = 1; off <= 8; off <<= 1)
#pragma unroll
            for (int m = 0; m < 2; ++m)
#pragma unroll
                for (int r = 0; r < 4; ++r)
                    rs_[m][r] += __shfl_xor(rs_[m][r], off);
        if (lr == 0) {
#pragma unroll
            for (int m = 0; m < 2; ++m)
#pragma unroll
                for (int r = 0; r < 4; ++r)
                    red[(32 * wq + 16 * m + 4 * quad + r) * 2 + wl] = rs_[m][r];
        }
        __syncthreads();                            // B1: E + row partial sums ready

        float invr[2][4];
#pragma unroll
        for (int m = 0; m < 2; ++m)
#pragma unroll
            for (int r = 0; r < 4; ++r) {
                const int row = 32 * wq + 16 * m + 4 * quad + r;
                invr[m][r] = 1.0f / (red[row * 2] + red[row * 2 + 1]);
            }

        // ---- phase 2: attn[128q x 256d]; wave (wq,wl): q-strip 32, d-strip 128
        f32x4 a_acc[2][8];
#pragma unroll
        for (int m = 0; m < 2; ++m)
#pragma unroll
            for (int nn = 0; nn < 8; ++nn) a_acc[m][nn] = vz;

        for (int kc = 0; kc < 4; ++kc) {
            const int l0 = kc * 32 + quad * 8;
            bf16x8 af[2], bf[8];
#pragma unroll
            for (int m = 0; m < 2; ++m)
                af[m] = lds16(E + (32 * wq + 16 * m + lr) * 136 + l0);
#pragma unroll
            for (int nn = 0; nn < 8; ++nn) {
                const int d = 128 * wl + 16 * nn + lr;
                bf[nn] = ldg16(sdl + d * LSZ + l0);
            }
#pragma unroll
            for (int m = 0; m < 2; ++m)
#pragma unroll
                for (int nn = 0; nn < 8; ++nn)
                    a_acc[m][nn] = mfma16(af[m], bf[nn], a_acc[m][nn]);
        }
#pragma unroll
        for (int m = 0; m < 2; ++m)
#pragma unroll
            for (int nn = 0; nn < 8; ++nn)
#pragma unroll
                for (int r = 0; r < 4; ++r)
                    attnL[(32 * wq + 16 * m + 4 * quad + r) * 264 + 128 * wl + 16 * nn + lr]
                        = f2bf(a_acc[m][nn][r] * invr[m][r]);
        __syncthreads();                            // B2: attn ready

        // ---- phase 3: X[128q x 256e] += attn . Wcat_n^T; e-strip 128 per wl
        for (int kc = 0; kc < 8; ++kc) {
            const int d0 = kc * 32 + quad * 8;
            bf16x8 af[2], bf[8];
#pragma unroll
            for (int m = 0; m < 2; ++m)
                af[m] = lds16(attnL + (32 * wq + 16 * m + lr) * 264 + d0);
#pragma unroll
            for (int nn = 0; nn < 8; ++nn) {
                const int e = 128 * wl + 16 * nn + lr;
                bf[nn] = ldg16(wcat + e * (NCTX * IDF) + d0);
            }
#pragma unroll
            for (int m = 0; m < 2; ++m)
#pragma unroll
                for (int nn = 0; nn < 8; ++nn)
                    x_acc[m][nn] = mfma16(af[m], bf[nn], x_acc[m][nn]);
        }
        // Hazards: next-n E writes happen after B2 (all E reads done);
        // next-n attnL writes happen after next B1, which every wave reaches
        // only after finishing this n's phase-3 attnL reads.
    }

    // ---- epilogue: bias + relu + residual + LayerNorm(eps=0) ----
    float gv[8], bv[8], wv[8];
    int ec[8];
#pragma unroll
    for (int nn = 0; nn < 8; ++nn) {
        ec[nn] = 128 * wl + 16 * nn + lr;
        wv[nn] = Wb[ec[nn]];
        gv[nn] = gam_p[ec[nn]];
        bv[nn] = bet_p[ec[nn]];
    }
    float s1[2][4], s2[2][4];
#pragma unroll
    for (int m = 0; m < 2; ++m)
#pragma unroll
        for (int r = 0; r < 4; ++r) {
            const int row = 32 * wq + 16 * m + 4 * quad + r;
            const u16* th = T_hi + (long)(bq + row) * IDF;
            const u16* tl = T_lo + (long)(bq + row) * IDF;
            float a = 0.f, q2 = 0.f;
#pragma unroll
            for (int nn = 0; nn < 8; ++nn) {
                const float resid = bf2f(th[ec[nn]]) + bf2f(tl[ec[nn]]);
                const float v = fmaxf(x_acc[m][nn][r] + wv[nn], 0.f) + resid;
                x_acc[m][nn][r] = v;
                a += v;
                q2 += v * v;
            }
            s1[m][r] = a;
            s2[m][r] = q2;
        }
#pragma unroll
    for (int off = 1; off <= 8; off <<= 1)
#pragma unroll
        for (int m = 0; m < 2; ++m)
#pragma unroll
            for (int r = 0; r < 4; ++r) {
                s1[m][r] += __shfl_xor(s1[m][r], off);
                s2[m][r] += __shfl_xor(s2[m][r], off);
            }
    if (lr == 0) {
#pragma unroll
        for (int m = 0; m < 2; ++m)
#pragma unroll
            for (int r = 0; r < 4; ++r) {
                const int row = 32 * wq + 16 * m + 4 * quad + r;
                red2[row * 4 + wl * 2]     = s1[m][r];
                red2[row * 4 + wl * 2 + 1] = s2[m][r];
            }
    }
    __syncthreads();
#pragma unroll
    for (int m = 0; m < 2; ++m)
#pragma unroll
        for (int r = 0; r < 4; ++r) {
            const int row = 32 * wq + 16 * m + 4 * quad + r;
            const float S1 = red2[row * 4] + red2[row * 4 + 2];
            const float S2 = red2[row * 4 + 1] + red2[row * 4 + 3];
            const float mu = S1 * (1.f / 256.f);
            const float rs = rsqrtf(S2 * (1.f / 256.f) - mu * mu);
            float* op = out + (long)(bq + row) * IDF;
#pragma unroll
            for (int nn = 0; nn < 8; ++nn)
                op[ec[nn]] = (x_acc[m][nn][r] - mu) * rs * gv[nn] + bv[nn];
        }
}

// ---------------- launch ----------------
extern "C" void kernel_launch(void* const* d_in, const int* in_sizes, int n_in,
                              void* d_out, int out_size, void* d_ws, size_t ws_size,
                              hipStream_t stream) {
    const float* input    = (const float*)d_in[0];
    const float* contexts = (const float*)d_in[1];
    const float* Wc       = (const float*)d_in[2];
    const float* Wcat     = (const float*)d_in[3];
    const float* Wb       = (const float*)d_in[4];
    const float* gamma    = (const float*)d_in[5];
    const float* beta     = (const float*)d_in[6];
    float* out = (float*)d_out;

    char* ws = (char*)d_ws;
    size_t off = 0;
    u16* Wc_hi   = (u16*)(ws + off); off += (size_t)IDF * CDF * 2;
    u16* Wc_lo   = (u16*)(ws + off); off += (size_t)IDF * CDF * 2;
    u16* Wcat_bf = (u16*)(ws + off); off += (size_t)IDF * NCTX * IDF * 2;
    u16* T_hi    = (u16*)(ws + off); off += (size_t)BSZ * QSZ * IDF * 2;
    u16* T_lo    = (u16*)(ws + off); off += (size_t)BSZ * QSZ * IDF * 2;
    u16* ctxT    = (u16*)(ws + off); off += (size_t)NCTX * BSZ * LSZ * CDF * 2;
    u16* sTT_hi  = (u16*)(ws + off); off += (size_t)NCTX * BSZ * LSZ * IDF * 2;
    u16* sTT_lo  = (u16*)(ws + off); off += (size_t)NCTX * BSZ * LSZ * IDF * 2;
    u16* s_dl    = (u16*)(ws + off); off += (size_t)NCTX * BSZ * IDF * LSZ * 2;
    (void)in_sizes; (void)n_in; (void)out_size; (void)ws_size;

    k1a_conv<<<3072, 256, 0, stream>>>(Wc, Wcat, Wc_hi, Wc_lo, Wcat_bf);
    k1b_tgt<<<dim3(QSZ / 128, IDF / 32, BSZ), 256, 0, stream>>>(input, T_hi, T_lo);
    k1c_ctx<<<dim3(CDF / 32, NCTX * BSZ), 256, 0, stream>>>(contexts, ctxT);
    k2_src<<<dim3(2, NCTX * BSZ), 256, 0, stream>>>(Wc_hi, Wc_lo, ctxT, sTT_hi, sTT_lo, s_dl);
    k3_attn<<<dim3(256), 512, 0, stream>>>(T_hi, T_lo, sTT_hi, sTT_lo, s_dl,
                                           Wcat_bf, Wb, gamma, beta, out);
}